// Round 1
// baseline (158.899 us; speedup 1.0000x reference)
//
#include <hip/hip_runtime.h>
#include <math.h>

#define L 4096
#define JC 128   // j-chunk per block in pair kernel

// AA order 'ACDEFGHIKLMNPQRSTVWYX'
__constant__ float c_charge[21] = {0.f,0.f,-1.f,-1.f,0.f,0.f,0.5f,0.f,1.f,0.f,0.f,0.f,0.f,0.f,1.f,0.f,0.f,0.f,0.f,0.f,0.f};
__constant__ float c_hydro[21]  = {1.8f,2.5f,-3.5f,-3.5f,2.8f,-0.4f,-3.2f,4.5f,-3.9f,3.8f,1.9f,-3.5f,-1.6f,-3.5f,-4.5f,-0.8f,-0.7f,4.2f,-0.9f,-1.3f,0.f};
__constant__ float c_phi0[21]   = {-60.f,-60.f,-60.f,-60.f,-60.f,-75.f,-60.f,-60.f,-60.f,-60.f,-60.f,-60.f,-65.f,-60.f,-60.f,-60.f,-60.f,-60.f,-60.f,-60.f,-60.f};
__constant__ float c_psi0[21]   = {-45.f,-45.f,-45.f,-45.f,-45.f,-60.f,-45.f,-45.f,-45.f,-45.f,-45.f,-45.f,-30.f,-45.f,-45.f,-45.f,-45.f,-45.f,-45.f,-45.f,-45.f};
__constant__ float c_wid[21]    = {25.f,25.f,25.f,25.f,25.f,40.f,25.f,25.f,25.f,25.f,25.f,25.f,20.f,25.f,25.f,25.f,25.f,25.f,25.f,25.f,25.f};

// ws float layout:
// [0..15]  scalar accum: 0 bond, 1 angle, 2 rama, 3 ent, 4 smooth, 5 electro, 6 hbond, 7 solv, 8 rot
// [16 + 0*L .. )  Nat (3L)
// [16 + 3*L]      Oat (3L)
// [16 + 6*L]      Vco (3L)   O - C
// [16 + 9*L]      Nco (L)    max(|Vco|,1e-8)
// [16 + 10*L]     Cb  (3L)   ideal CB
// [16 + 13*L]     Q   (L)
// [16 + 14*L]     Idl (L)    2.9*(1+0.1*(alpha-1))
// [16 + 15*L]     Dens(L)
// [16 + 16*L]     DminB (L, uint bits of squared dist)
#define WS_NAT(ws)  ((ws)+16)
#define WS_OAT(ws)  ((ws)+16+3*L)
#define WS_VCO(ws)  ((ws)+16+6*L)
#define WS_NCO(ws)  ((ws)+16+9*L)
#define WS_CB(ws)   ((ws)+16+10*L)
#define WS_Q(ws)    ((ws)+16+13*L)
#define WS_IDL(ws)  ((ws)+16+14*L)
#define WS_DENS(ws) ((ws)+16+15*L)
#define WS_DMIN(ws) ((unsigned int*)((ws)+16+16*L))

struct f3 { float x, y, z; };
__device__ inline f3 mk(float x, float y, float z){ f3 r{x,y,z}; return r; }
__device__ inline f3 sub3(f3 a, f3 b){ return mk(a.x-b.x, a.y-b.y, a.z-b.z); }
__device__ inline f3 add3(f3 a, f3 b){ return mk(a.x+b.x, a.y+b.y, a.z+b.z); }
__device__ inline f3 scl3(f3 a, float s){ return mk(a.x*s, a.y*s, a.z*s); }
__device__ inline float dot3(f3 a, f3 b){ return a.x*b.x + a.y*b.y + a.z*b.z; }
__device__ inline f3 crs3(f3 a, f3 b){ return mk(a.y*b.z-a.z*b.y, a.z*b.x-a.x*b.z, a.x*b.y-a.y*b.x); }
__device__ inline float nrm3(f3 a){ return sqrtf(dot3(a,a)); }
__device__ inline f3 unit3(f3 a){ float n = fmaxf(nrm3(a), 1e-8f); return mk(a.x/n, a.y/n, a.z/n); }

__device__ inline float dihedral(f3 p0, f3 p1, f3 p2, f3 p3){
  f3 b0 = sub3(p1,p0), b1 = sub3(p2,p1), b2 = sub3(p3,p2);
  f3 b1n = unit3(b1);
  f3 v = sub3(b0, scl3(b1n, dot3(b0,b1n)));
  f3 w = sub3(b2, scl3(b1n, dot3(b2,b1n)));
  float x = dot3(v,w);
  float y = dot3(crs3(b1n,v), w);
  return atan2f(y + 1e-8f, x + 1e-8f);
}

__device__ inline float wave_reduce(float v){
  #pragma unroll
  for (int off = 32; off > 0; off >>= 1) v += __shfl_down(v, off, 64);
  return v;
}

__global__ __launch_bounds__(256) void init_kernel(float* __restrict__ ws){
  int i = blockIdx.x*256 + threadIdx.x;            // 0..4095
  if (i < 16) ws[i] = 0.f;
  WS_DENS(ws)[i] = 0.f;
  WS_DMIN(ws)[i] = 0x7F800000u;                    // +inf
}

__global__ __launch_bounds__(256) void residue_kernel(const float* __restrict__ ca,
    const float* __restrict__ alpha, const int* __restrict__ seq, float* __restrict__ ws)
{
  int i = blockIdx.x*256 + threadIdx.x;
  float* S = ws;
  f3 c0 = mk(ca[3*i], ca[3*i+1], ca[3*i+2]);
  f3 cm = c0, cp = c0;
  if (i > 0)   cm = mk(ca[3*(i-1)], ca[3*(i-1)+1], ca[3*(i-1)+2]);
  if (i < L-1) cp = mk(ca[3*(i+1)], ca[3*(i+1)+1], ca[3*(i+1)+2]);
  f3 vnm = unit3(sub3(c0, cm));   // vn[i-1] (valid for i>=1)
  f3 vni = unit3(sub3(cp, c0));   // vn[i]   (valid for i<=L-2)

  f3 N = (i == 0)  ? sub3(c0, scl3(vni, 1.45f)) : sub3(c0, scl3(vnm, 1.45f));
  f3 C = (i < L-1) ? add3(c0, scl3(vni, 1.52f)) : add3(c0, scl3(vnm, 1.52f));
  f3 perp = crs3(sub3(C,c0), sub3(N,c0));
  float pn = nrm3(perp);
  if (pn > 1e-6f) perp = scl3(perp, 1.f/fmaxf(pn, 1e-30f));
  f3 O = (i < L-1) ? add3(C, scl3(perp, 1.24f)) : mk(C.x, C.y + 1.24f, C.z);

  f3 sum = add3(sub3(N,c0), sub3(C,c0));
  f3 cbdir = unit3(mk(-sum.x, -sum.y, -sum.z));
  f3 cb = add3(c0, scl3(cbdir, 1.8f));

  f3 vco = sub3(O, C);
  float nco = fmaxf(nrm3(vco), 1e-8f);

  int sid = seq[i];
  float al = alpha[i];

  WS_NAT(ws)[3*i]=N.x; WS_NAT(ws)[3*i+1]=N.y; WS_NAT(ws)[3*i+2]=N.z;
  WS_OAT(ws)[3*i]=O.x; WS_OAT(ws)[3*i+1]=O.y; WS_OAT(ws)[3*i+2]=O.z;
  WS_VCO(ws)[3*i]=vco.x; WS_VCO(ws)[3*i+1]=vco.y; WS_VCO(ws)[3*i+2]=vco.z;
  WS_NCO(ws)[i]=nco;
  WS_CB(ws)[3*i]=cb.x; WS_CB(ws)[3*i+1]=cb.y; WS_CB(ws)[3*i+2]=cb.z;
  WS_Q(ws)[i]=c_charge[sid];
  WS_IDL(ws)[i]=2.9f*(1.f + 0.1f*(al - 1.f));

  // ---- O(L) energy terms ----
  float bond = 0.f, angle = 0.f, rama = 0.f, smooth = 0.f;
  float ent = al * logf(al + 1e-8f);
  if (i < L-1) {
    float alp = alpha[i+1];
    float d = nrm3(sub3(cp, c0));
    float tp = 0.5f*(3.8f*(1.f+0.1f*(al-1.f)) + 3.8f*(1.f+0.1f*(alp-1.f)));
    bond = (d - tp)*(d - tp);
    smooth = (alp - al)*(alp - al);
  }
  if (i >= 1 && i <= L-2) {
    f3 v1 = unit3(sub3(cm, c0));
    f3 v2 = unit3(sub3(cp, c0));
    float cang = dot3(v1, v2);
    float ct = cosf(1.5708f*(1.f + 0.1f*(al - 1.f)));
    angle = (cang - ct)*(cang - ct);

    f3 Cm1 = add3(cm, scl3(vnm, 1.52f));   // Catm[i-1]
    f3 Np1 = sub3(cp, scl3(vni, 1.45f));   // Natm[i+1]
    const float deg = 57.29577951308232f;
    float phi = dihedral(Cm1, N, c0, C) * deg;
    float psi = dihedral(N, c0, C, Np1) * deg;
    float weff = c_wid[sid]*(1.f + 0.1f*(al - 1.f)) + 1e-8f;
    float dphi = (phi - c_phi0[sid]) / weff;
    float dpsi = (psi - c_psi0[sid]) / weff;
    rama = dphi*dphi + dpsi*dpsi;
  }
  bond = wave_reduce(bond); angle = wave_reduce(angle); rama = wave_reduce(rama);
  ent  = wave_reduce(ent);  smooth = wave_reduce(smooth);
  if ((threadIdx.x & 63) == 0) {
    atomicAdd(&S[0], bond); atomicAdd(&S[1], angle); atomicAdd(&S[2], rama);
    atomicAdd(&S[3], ent);  atomicAdd(&S[4], smooth);
  }
}

__global__ __launch_bounds__(256) void pair_kernel(const float* __restrict__ ca, float* __restrict__ ws)
{
  float* S = ws;
  const float* Nat = WS_NAT(ws);
  const float* Oat = WS_OAT(ws);
  const float* Vco = WS_VCO(ws);
  const float* Nco = WS_NCO(ws);
  const float* Cb  = WS_CB(ws);
  const float* Q   = WS_Q(ws);
  const float* Idl = WS_IDL(ws);

  int tid = threadIdx.x;
  int i = blockIdx.x*256 + tid;
  int j0 = blockIdx.y*JC;

  __shared__ float sj[JC][8];
  for (int t = tid; t < JC; t += 256) {
    int j = j0 + t;
    sj[t][0] = ca[3*j]; sj[t][1] = ca[3*j+1]; sj[t][2] = ca[3*j+2];
    sj[t][3] = Nat[3*j]; sj[t][4] = Nat[3*j+1]; sj[t][5] = Nat[3*j+2];
    sj[t][6] = Q[j];
    sj[t][7] = 0.f;
  }
  __syncthreads();

  float cix = ca[3*i], ciy = ca[3*i+1], ciz = ca[3*i+2];
  float Oix = Oat[3*i], Oiy = Oat[3*i+1], Oiz = Oat[3*i+2];
  float vcx = Vco[3*i], vcy = Vco[3*i+1], vcz = Vco[3*i+2];
  float ncoi = Nco[i], qi = Q[i], idl = Idl[i];
  float cbx = Cb[3*i], cby = Cb[3*i+1], cbz = Cb[3*i+2];

  float e_el = 0.f, e_hb = 0.f, dens = 0.f, dmin2 = 3.0e38f;

  #pragma unroll 4
  for (int jj = 0; jj < JC; ++jj) {
    float cjx = sj[jj][0], cjy = sj[jj][1], cjz = sj[jj][2];
    float dx = cix - cjx, dy = ciy - cjy, dz = ciz - cjz;
    float d2 = dx*dx + dy*dy + dz*dz;
    float D = sqrtf(d2);
    bool self = ((j0 + jj) == i);
    if (D < 10.f) dens += 1.f;
    float qq = qi * sj[jj][6];
    if (qq != 0.f && !self) {
      float De = D + 1e-6f;
      e_el += qq * __expf(-0.1f*De) / (80.f*De);
    }
    float rx = cbx - cjx, ry = cby - cjy, rz = cbz - cjz;
    float r2 = rx*rx + ry*ry + rz*rz;
    if (!self && r2 < dmin2) dmin2 = r2;
    float nx = sj[jj][3] - Oix, ny = sj[jj][4] - Oiy, nz = sj[jj][5] - Oiz;
    float h2 = nx*nx + ny*ny + nz*nz;
    float Dh = sqrtf(h2);
    if (Dh > 2.5f && Dh < 3.5f) {
      float align = (vcx*nx + vcy*ny + vcz*nz) / (ncoi * fmaxf(Dh, 1e-8f));
      float t = (Dh - idl) * 3.33333333333333f;
      e_hb -= align * __expf(-t*t);
    }
  }

  e_el = wave_reduce(e_el);
  e_hb = wave_reduce(e_hb);
  if ((tid & 63) == 0) { atomicAdd(&S[5], e_el); atomicAdd(&S[6], e_hb); }
  atomicAdd(&WS_DENS(ws)[i], dens);
  atomicMin(&WS_DMIN(ws)[i], __float_as_uint(dmin2));
}

__global__ __launch_bounds__(256) void post_kernel(const int* __restrict__ seq, float* __restrict__ ws)
{
  int i = blockIdx.x*256 + threadIdx.x;
  float* S = ws;
  float density = WS_DENS(ws)[i];
  float burial = 1.f - expf(-density * 0.05f);
  float hy = c_hydro[seq[i]];
  float sterm = (hy > 0.f) ? hy*(1.f - burial) : (-hy*burial);
  float dmin = sqrtf(__uint_as_float(WS_DMIN(ws)[i]));
  bool inc = (seq[i] != 5) && (i > 0) && (i < L-1);
  float rterm = inc ? fmaxf(4.f - dmin, 0.f) : 0.f;
  sterm = wave_reduce(sterm);
  rterm = wave_reduce(rterm);
  if ((threadIdx.x & 63) == 0) { atomicAdd(&S[7], sterm); atomicAdd(&S[8], rterm); }
}

__global__ void combine_kernel(const float* __restrict__ ws, float* __restrict__ out)
{
  const float* S = ws;
  const float Lf = (float)L;
  float e = S[0] / (Lf - 1.f)                 // W_BOND * mean
          + S[1] / (Lf - 2.f)                 // W_ANGLE * mean
          + 0.5f * S[2] / (Lf - 2.f)          // W_RAMA * sum/mask
          + 0.5f * S[5] / (Lf * Lf)           // W_ELECTRO * mean
          + S[6] / (Lf * Lf)                  // W_HBOND * mean
          + 0.5f * S[7] / Lf                  // W_SOLVENT * mean
          + 0.5f * S[8] / (Lf - 2.f)          // W_ROTAMER * sum/(L-2)
          + 0.01f * (-S[3] / Lf)              // W_AENT * ent
          + 0.01f * S[4] / (Lf - 1.f);        // W_ASMOOTH * smooth
  out[0] = e;
}

extern "C" void kernel_launch(void* const* d_in, const int* in_sizes, int n_in,
                              void* d_out, int out_size, void* d_ws, size_t ws_size,
                              hipStream_t stream) {
  (void)in_sizes; (void)n_in; (void)out_size; (void)ws_size;
  const float* ca    = (const float*)d_in[0];
  const float* alpha = (const float*)d_in[1];
  const int*   seq   = (const int*)d_in[2];
  float* out = (float*)d_out;
  float* ws  = (float*)d_ws;

  init_kernel<<<L/256, 256, 0, stream>>>(ws);
  residue_kernel<<<L/256, 256, 0, stream>>>(ca, alpha, seq, ws);
  pair_kernel<<<dim3(L/256, L/JC), 256, 0, stream>>>(ca, ws);
  post_kernel<<<L/256, 256, 0, stream>>>(seq, ws);
  combine_kernel<<<1, 1, 0, stream>>>(ws, out);
}

// Round 6
// 89.019 us; speedup vs baseline: 1.7850x; 1.7850x over previous
//
#include <hip/hip_runtime.h>
#include <math.h>

#define L 4096
#define JC 32            // j-chunk per block in pair kernel
#define NJB (L/JC)       // 128 j-chunks
#define NIB (L/256)      // 16 i-blocks
#define NBLK (NIB*NJB)   // 2048 pair blocks

// AA order 'ACDEFGHIKLMNPQRSTVWYX'
__constant__ float c_charge[21] = {0.f,0.f,-1.f,-1.f,0.f,0.f,0.5f,0.f,1.f,0.f,0.f,0.f,0.f,0.f,1.f,0.f,0.f,0.f,0.f,0.f,0.f};
__constant__ float c_hydro[21]  = {1.8f,2.5f,-3.5f,-3.5f,2.8f,-0.4f,-3.2f,4.5f,-3.9f,3.8f,1.9f,-3.5f,-1.6f,-3.5f,-4.5f,-0.8f,-0.7f,4.2f,-0.9f,-1.3f,0.f};
__constant__ float c_phi0[21]   = {-60.f,-60.f,-60.f,-60.f,-60.f,-75.f,-60.f,-60.f,-60.f,-60.f,-60.f,-60.f,-65.f,-60.f,-60.f,-60.f,-60.f,-60.f,-60.f,-60.f,-60.f};
__constant__ float c_psi0[21]   = {-45.f,-45.f,-45.f,-45.f,-45.f,-60.f,-45.f,-45.f,-45.f,-45.f,-45.f,-45.f,-30.f,-45.f,-45.f,-45.f,-45.f,-45.f,-45.f,-45.f,-45.f};
__constant__ float c_wid[21]    = {25.f,25.f,25.f,25.f,25.f,40.f,25.f,25.f,25.f,25.f,25.f,25.f,20.f,25.f,25.f,25.f,25.f,25.f,25.f,25.f,25.f};

// ws float layout (all float4 regions 16B-aligned: offsets are multiples of 4L):
// 0     : PA  [L] float4  (ca.xyz, charge)
// 4L    : PB  [L] float4  (N.xyz, 0)
// 8L    : PI1 [L] float4  (O.xyz, nco)
// 12L   : PI2 [L] float4  (vco.xyz, ideal)
// 16L   : PI3 [L] float4  (cb.xyz, 0)
// 20L   : DENS[L]
// 21L   : DMIN[L] (uint bits of squared dist)
// 22L   : RP  [5*64]  residue per-wave partials: q*64+blk (bond,angle,rama,ent,smooth)
// 22L+320 : BPel[NBLK], then BPhb[NBLK]
#define WS_PA(ws)   ((float4*)(ws))
#define WS_PB(ws)   ((float4*)((ws)+4*L))
#define WS_PI1(ws)  ((float4*)((ws)+8*L))
#define WS_PI2(ws)  ((float4*)((ws)+12*L))
#define WS_PI3(ws)  ((float4*)((ws)+16*L))
#define WS_DENS(ws) ((ws)+20*L)
#define WS_DMIN(ws) ((unsigned int*)((ws)+21*L))
#define WS_RP(ws)   ((ws)+22*L)
#define WS_BPEL(ws) ((ws)+22*L+320)
#define WS_BPHB(ws) ((ws)+22*L+320+NBLK)

struct f3 { float x, y, z; };
__device__ inline f3 mk(float x, float y, float z){ f3 r{x,y,z}; return r; }
__device__ inline f3 sub3(f3 a, f3 b){ return mk(a.x-b.x, a.y-b.y, a.z-b.z); }
__device__ inline f3 add3(f3 a, f3 b){ return mk(a.x+b.x, a.y+b.y, a.z+b.z); }
__device__ inline f3 scl3(f3 a, float s){ return mk(a.x*s, a.y*s, a.z*s); }
__device__ inline float dot3(f3 a, f3 b){ return a.x*b.x + a.y*b.y + a.z*b.z; }
__device__ inline f3 crs3(f3 a, f3 b){ return mk(a.y*b.z-a.z*b.y, a.z*b.x-a.x*b.z, a.x*b.y-a.y*b.x); }
__device__ inline float nrm3(f3 a){ return sqrtf(dot3(a,a)); }
__device__ inline f3 unit3(f3 a){ float n = fmaxf(nrm3(a), 1e-8f); return mk(a.x/n, a.y/n, a.z/n); }

__device__ inline float dihedral(f3 p0, f3 p1, f3 p2, f3 p3){
  f3 b0 = sub3(p1,p0), b1 = sub3(p2,p1), b2 = sub3(p3,p2);
  f3 b1n = unit3(b1);
  f3 v = sub3(b0, scl3(b1n, dot3(b0,b1n)));
  f3 w = sub3(b2, scl3(b1n, dot3(b2,b1n)));
  float x = dot3(v,w);
  float y = dot3(crs3(b1n,v), w);
  return atan2f(y + 1e-8f, x + 1e-8f);
}

__device__ inline float wave_reduce(float v){
  #pragma unroll
  for (int off = 32; off > 0; off >>= 1) v += __shfl_down(v, off, 64);
  return v;
}

// 64 blocks x 64 threads: one wave per block, i = blk*64+lane
__global__ __launch_bounds__(64) void residue_kernel(const float* __restrict__ ca,
    const float* __restrict__ alpha, const int* __restrict__ seq, float* __restrict__ ws)
{
  int i = blockIdx.x*64 + threadIdx.x;
  f3 c0 = mk(ca[3*i], ca[3*i+1], ca[3*i+2]);
  f3 cm = c0, cp = c0;
  if (i > 0)   cm = mk(ca[3*(i-1)], ca[3*(i-1)+1], ca[3*(i-1)+2]);
  if (i < L-1) cp = mk(ca[3*(i+1)], ca[3*(i+1)+1], ca[3*(i+1)+2]);
  f3 vnm = unit3(sub3(c0, cm));   // vn[i-1] (valid for i>=1)
  f3 vni = unit3(sub3(cp, c0));   // vn[i]   (valid for i<=L-2)

  f3 N = (i == 0)  ? sub3(c0, scl3(vni, 1.45f)) : sub3(c0, scl3(vnm, 1.45f));
  f3 C = (i < L-1) ? add3(c0, scl3(vni, 1.52f)) : add3(c0, scl3(vnm, 1.52f));
  f3 perp = crs3(sub3(C,c0), sub3(N,c0));
  float pn = nrm3(perp);
  if (pn > 1e-6f) perp = scl3(perp, 1.f/fmaxf(pn, 1e-30f));
  f3 O = (i < L-1) ? add3(C, scl3(perp, 1.24f)) : mk(C.x, C.y + 1.24f, C.z);

  f3 sum = add3(sub3(N,c0), sub3(C,c0));
  f3 cbdir = unit3(mk(-sum.x, -sum.y, -sum.z));
  f3 cb = add3(c0, scl3(cbdir, 1.8f));

  f3 vco = sub3(O, C);
  float nco = fmaxf(nrm3(vco), 1e-8f);

  int sid = seq[i];
  float al = alpha[i];

  float4 pa; pa.x=c0.x; pa.y=c0.y; pa.z=c0.z; pa.w=c_charge[sid];
  float4 pb; pb.x=N.x; pb.y=N.y; pb.z=N.z; pb.w=0.f;
  float4 p1; p1.x=O.x; p1.y=O.y; p1.z=O.z; p1.w=nco;
  float4 p2; p2.x=vco.x; p2.y=vco.y; p2.z=vco.z; p2.w=2.9f*(1.f + 0.1f*(al - 1.f));
  float4 p3; p3.x=cb.x; p3.y=cb.y; p3.z=cb.z; p3.w=0.f;
  WS_PA(ws)[i]=pa; WS_PB(ws)[i]=pb; WS_PI1(ws)[i]=p1; WS_PI2(ws)[i]=p2; WS_PI3(ws)[i]=p3;
  WS_DENS(ws)[i]=0.f;
  WS_DMIN(ws)[i]=0x7F800000u;   // +inf

  // ---- O(L) energy terms ----
  float bond = 0.f, angle = 0.f, rama = 0.f, smooth = 0.f;
  float ent = al * logf(al + 1e-8f);
  if (i < L-1) {
    float alp = alpha[i+1];
    float d = nrm3(sub3(cp, c0));
    float tp = 0.5f*(3.8f*(1.f+0.1f*(al-1.f)) + 3.8f*(1.f+0.1f*(alp-1.f)));
    bond = (d - tp)*(d - tp);
    smooth = (alp - al)*(alp - al);
  }
  if (i >= 1 && i <= L-2) {
    f3 v1 = unit3(sub3(cm, c0));
    f3 v2 = unit3(sub3(cp, c0));
    float cang = dot3(v1, v2);
    float ct = cosf(1.5708f*(1.f + 0.1f*(al - 1.f)));
    angle = (cang - ct)*(cang - ct);

    f3 Cm1 = add3(cm, scl3(vnm, 1.52f));   // Catm[i-1]
    f3 Np1 = sub3(cp, scl3(vni, 1.45f));   // Natm[i+1]
    const float deg = 57.29577951308232f;
    float phi = dihedral(Cm1, N, c0, C) * deg;
    float psi = dihedral(N, c0, C, Np1) * deg;
    float weff = c_wid[sid]*(1.f + 0.1f*(al - 1.f)) + 1e-8f;
    float dphi = (phi - c_phi0[sid]) / weff;
    float dpsi = (psi - c_psi0[sid]) / weff;
    rama = dphi*dphi + dpsi*dpsi;
  }
  bond = wave_reduce(bond); angle = wave_reduce(angle); rama = wave_reduce(rama);
  ent  = wave_reduce(ent);  smooth = wave_reduce(smooth);
  if (threadIdx.x == 0) {
    float* RP = WS_RP(ws);
    int b = blockIdx.x;
    RP[0*64+b]=bond; RP[1*64+b]=angle; RP[2*64+b]=rama; RP[3*64+b]=ent; RP[4*64+b]=smooth;
  }
}

__global__ __launch_bounds__(256) void pair_kernel(float* __restrict__ ws)
{
  const float4* __restrict__ PA  = WS_PA(ws);
  const float4* __restrict__ PB  = WS_PB(ws);
  const float4* __restrict__ PI1 = WS_PI1(ws);
  const float4* __restrict__ PI2 = WS_PI2(ws);
  const float4* __restrict__ PI3 = WS_PI3(ws);

  int t = threadIdx.x;
  int i = blockIdx.x*256 + t;
  int j0 = blockIdx.y*JC;

  __shared__ float4 sA[JC];   // ca.xyz, q
  __shared__ float4 sB[JC];   // N.xyz, -
  if (t < JC)           sA[t]     = PA[j0 + t];
  else if (t < 2*JC)    sB[t-JC]  = PB[j0 + t - JC];

  float4 ai = PA[i];
  float4 i1 = PI1[i];
  float4 i2 = PI2[i];
  float4 i3 = PI3[i];
  float qi = ai.w, ncoi = i1.w, idl = i2.w;
  __syncthreads();

  float e_el = 0.f, e_hb = 0.f, dens = 0.f, dmin2 = 3.0e38f;

  #pragma unroll
  for (int jj = 0; jj < JC; ++jj) {
    float4 a = sA[jj];
    float4 b = sB[jj];
    float dx = ai.x - a.x, dy = ai.y - a.y, dz = ai.z - a.z;
    float d2 = dx*dx + dy*dy + dz*dz;
    if (d2 < 100.f) dens += 1.f;
    bool self = ((j0 + jj) == i);
    float rx = i3.x - a.x, ry = i3.y - a.y, rz = i3.z - a.z;
    float r2 = rx*rx + ry*ry + rz*rz;
    r2 = self ? 3.0e38f : r2;
    dmin2 = fminf(dmin2, r2);
    if (a.w != 0.f) {                       // qj uniform -> whole wave skips 76% of chunks
      float qq = self ? 0.f : qi * a.w;
      float D  = sqrtf(d2);
      float De = D + 1e-6f;
      e_el += qq * __expf(-0.1f*De) * __builtin_amdgcn_rcpf(80.f*De);
    }
    float nx = b.x - i1.x, ny = b.y - i1.y, nz = b.z - i1.z;
    float h2 = nx*nx + ny*ny + nz*nz;
    if (h2 > 6.25f && h2 < 12.25f) {        // rare (~8%/wave)
      float Dh = sqrtf(h2);
      float num = i2.x*nx + i2.y*ny + i2.z*nz;
      float tt  = (Dh - idl) * 3.33333333333333f;
      e_hb -= num * __builtin_amdgcn_rcpf(ncoi * Dh) * __expf(-tt*tt);
    }
  }

  e_el = wave_reduce(e_el);
  e_hb = wave_reduce(e_hb);
  __shared__ float sp[8];
  if ((t & 63) == 0) { sp[t>>6] = e_el; sp[4+(t>>6)] = e_hb; }
  __syncthreads();
  if (t == 0) {
    int b = blockIdx.y*NIB + blockIdx.x;
    WS_BPEL(ws)[b] = sp[0]+sp[1]+sp[2]+sp[3];
    WS_BPHB(ws)[b] = sp[4]+sp[5]+sp[6]+sp[7];
  }
  atomicAdd(&WS_DENS(ws)[i], dens);
  atomicMin(&WS_DMIN(ws)[i], __float_as_uint(dmin2));
}

// single block, 1024 threads: sum partials + solvent/rotamer + combine
__global__ __launch_bounds__(1024) void final_kernel(const int* __restrict__ seq,
    const float* __restrict__ ws, float* __restrict__ out)
{
  int t = threadIdx.x;
  const float* BPel = WS_BPEL(ws);
  const float* BPhb = WS_BPHB(ws);
  const float* RP = WS_RP(ws);

  float v0=0.f,v1=0.f,v2=0.f,v3=0.f,v4=0.f,v7=0.f,v8=0.f;
  float v5 = BPel[t] + BPel[t+1024];
  float v6 = BPhb[t] + BPhb[t+1024];
  if (t < 64) { v0=RP[t]; v1=RP[64+t]; v2=RP[128+t]; v3=RP[192+t]; v4=RP[256+t]; }

  #pragma unroll
  for (int k = 0; k < 4; ++k) {
    int i = t + k*1024;
    float density = WS_DENS((float*)ws)[i];
    float burial = 1.f - __expf(-density * 0.05f);
    float hy = c_hydro[seq[i]];
    v7 += (hy > 0.f) ? hy*(1.f - burial) : (-hy*burial);
    float dmin = sqrtf(__uint_as_float(((const unsigned int*)(ws+21*L))[i]));
    if (seq[i] != 5 && i > 0 && i < L-1) v8 += fmaxf(4.f - dmin, 0.f);
  }

  v0=wave_reduce(v0); v1=wave_reduce(v1); v2=wave_reduce(v2);
  v3=wave_reduce(v3); v4=wave_reduce(v4); v5=wave_reduce(v5);
  v6=wave_reduce(v6); v7=wave_reduce(v7); v8=wave_reduce(v8);

  __shared__ float red[16*9];
  int w = t >> 6;
  if ((t & 63) == 0) {
    red[w*9+0]=v0; red[w*9+1]=v1; red[w*9+2]=v2; red[w*9+3]=v3; red[w*9+4]=v4;
    red[w*9+5]=v5; red[w*9+6]=v6; red[w*9+7]=v7; red[w*9+8]=v8;
  }
  __syncthreads();
  if (t == 0) {
    float s[9];
    #pragma unroll
    for (int q = 0; q < 9; ++q) s[q] = 0.f;
    for (int ww = 0; ww < 16; ++ww)
      #pragma unroll
      for (int q = 0; q < 9; ++q) s[q] += red[ww*9+q];
    const float Lf = (float)L;
    out[0] = s[0] / (Lf - 1.f)            // bond
           + s[1] / (Lf - 2.f)            // angle
           + 0.5f * s[2] / (Lf - 2.f)     // rama
           + 0.5f * s[5] / (Lf * Lf)      // electro
           + s[6] / (Lf * Lf)             // hbond
           + 0.5f * s[7] / Lf             // solvent
           + 0.5f * s[8] / (Lf - 2.f)     // rotamer
           + 0.01f * (-s[3] / Lf)         // entropy
           + 0.01f * s[4] / (Lf - 1.f);   // smooth
  }
}

extern "C" void kernel_launch(void* const* d_in, const int* in_sizes, int n_in,
                              void* d_out, int out_size, void* d_ws, size_t ws_size,
                              hipStream_t stream) {
  (void)in_sizes; (void)n_in; (void)out_size; (void)ws_size;
  const float* ca    = (const float*)d_in[0];
  const float* alpha = (const float*)d_in[1];
  const int*   seq   = (const int*)d_in[2];
  float* out = (float*)d_out;
  float* ws  = (float*)d_ws;

  residue_kernel<<<64, 64, 0, stream>>>(ca, alpha, seq, ws);
  pair_kernel<<<dim3(NIB, NJB), 256, 0, stream>>>(ws);
  final_kernel<<<1, 1024, 0, stream>>>(seq, ws, out);
}

// Round 8
// 82.488 us; speedup vs baseline: 1.9263x; 1.0792x over previous
//
#include <hip/hip_runtime.h>
#include <math.h>

#define L 4096
#define JC 32            // j-chunk per block in pair kernel
#define NJB (L/JC)       // 128 j-chunks
#define NIB 8            // i-blocks (512 i's each: 2 i's per thread)
#define NBLK (NIB*NJB)   // 1024 pair blocks

// AA order 'ACDEFGHIKLMNPQRSTVWYX'
__constant__ float c_charge[21] = {0.f,0.f,-1.f,-1.f,0.f,0.f,0.5f,0.f,1.f,0.f,0.f,0.f,0.f,0.f,1.f,0.f,0.f,0.f,0.f,0.f,0.f};
__constant__ float c_hydro[21]  = {1.8f,2.5f,-3.5f,-3.5f,2.8f,-0.4f,-3.2f,4.5f,-3.9f,3.8f,1.9f,-3.5f,-1.6f,-3.5f,-4.5f,-0.8f,-0.7f,4.2f,-0.9f,-1.3f,0.f};
__constant__ float c_phi0[21]   = {-60.f,-60.f,-60.f,-60.f,-60.f,-75.f,-60.f,-60.f,-60.f,-60.f,-60.f,-60.f,-65.f,-60.f,-60.f,-60.f,-60.f,-60.f,-60.f,-60.f,-60.f};
__constant__ float c_psi0[21]   = {-45.f,-45.f,-45.f,-45.f,-45.f,-60.f,-45.f,-45.f,-45.f,-45.f,-45.f,-45.f,-30.f,-45.f,-45.f,-45.f,-45.f,-45.f,-45.f,-45.f,-45.f};
__constant__ float c_wid[21]    = {25.f,25.f,25.f,25.f,25.f,40.f,25.f,25.f,25.f,25.f,25.f,25.f,20.f,25.f,25.f,25.f,25.f,25.f,25.f,25.f,25.f};

// ws float layout (float4 regions 16B-aligned):
// 0   : PA  [L] float4  (ca.xyz, charge)
// 4L  : PB  [L] float4  (N.xyz, 0)
// 8L  : PI1 [L] float4  (O.xyz, nco)
// 12L : PI2 [L] float4  (vco.xyz, ideal)
// 16L : PI3 [L] float4  (cb.xyz, 0)
// 20L : DENS[L]
// 21L : DMIN[L] (uint bits of squared dist)
// 22L : RP  [5*64]  residue per-wave partials
// 22L+320 : BPel[NBLK], then BPhb[NBLK]
#define WS_PA(ws)   ((float4*)(ws))
#define WS_PB(ws)   ((float4*)((ws)+4*L))
#define WS_PI1(ws)  ((float4*)((ws)+8*L))
#define WS_PI2(ws)  ((float4*)((ws)+12*L))
#define WS_PI3(ws)  ((float4*)((ws)+16*L))
#define WS_DENS(ws) ((ws)+20*L)
#define WS_DMIN(ws) ((unsigned int*)((ws)+21*L))
#define WS_RP(ws)   ((ws)+22*L)
#define WS_BPEL(ws) ((ws)+22*L+320)
#define WS_BPHB(ws) ((ws)+22*L+320+NBLK)

struct f3 { float x, y, z; };
__device__ inline f3 mk(float x, float y, float z){ f3 r{x,y,z}; return r; }
__device__ inline f3 sub3(f3 a, f3 b){ return mk(a.x-b.x, a.y-b.y, a.z-b.z); }
__device__ inline f3 add3(f3 a, f3 b){ return mk(a.x+b.x, a.y+b.y, a.z+b.z); }
__device__ inline f3 scl3(f3 a, float s){ return mk(a.x*s, a.y*s, a.z*s); }
__device__ inline float dot3(f3 a, f3 b){ return a.x*b.x + a.y*b.y + a.z*b.z; }
__device__ inline f3 crs3(f3 a, f3 b){ return mk(a.y*b.z-a.z*b.y, a.z*b.x-a.x*b.z, a.x*b.y-a.y*b.x); }
__device__ inline float nrm3(f3 a){ return sqrtf(dot3(a,a)); }
__device__ inline f3 unit3(f3 a){ float n = fmaxf(nrm3(a), 1e-8f); return mk(a.x/n, a.y/n, a.z/n); }

__device__ inline float dihedral(f3 p0, f3 p1, f3 p2, f3 p3){
  f3 b0 = sub3(p1,p0), b1 = sub3(p2,p1), b2 = sub3(p3,p2);
  f3 b1n = unit3(b1);
  f3 v = sub3(b0, scl3(b1n, dot3(b0,b1n)));
  f3 w = sub3(b2, scl3(b1n, dot3(b2,b1n)));
  float x = dot3(v,w);
  float y = dot3(crs3(b1n,v), w);
  return atan2f(y + 1e-8f, x + 1e-8f);
}

__device__ inline float wave_reduce(float v){
  #pragma unroll
  for (int off = 32; off > 0; off >>= 1) v += __shfl_down(v, off, 64);
  return v;
}

// 64 blocks x 64 threads: one wave per block, i = blk*64+lane
__global__ __launch_bounds__(64) void residue_kernel(const float* __restrict__ ca,
    const float* __restrict__ alpha, const int* __restrict__ seq, float* __restrict__ ws)
{
  int i = blockIdx.x*64 + threadIdx.x;
  f3 c0 = mk(ca[3*i], ca[3*i+1], ca[3*i+2]);
  f3 cm = c0, cp = c0;
  if (i > 0)   cm = mk(ca[3*(i-1)], ca[3*(i-1)+1], ca[3*(i-1)+2]);
  if (i < L-1) cp = mk(ca[3*(i+1)], ca[3*(i+1)+1], ca[3*(i+1)+2]);
  f3 vnm = unit3(sub3(c0, cm));   // vn[i-1] (valid for i>=1)
  f3 vni = unit3(sub3(cp, c0));   // vn[i]   (valid for i<=L-2)

  f3 N = (i == 0)  ? sub3(c0, scl3(vni, 1.45f)) : sub3(c0, scl3(vnm, 1.45f));
  f3 C = (i < L-1) ? add3(c0, scl3(vni, 1.52f)) : add3(c0, scl3(vnm, 1.52f));
  f3 perp = crs3(sub3(C,c0), sub3(N,c0));
  float pn = nrm3(perp);
  if (pn > 1e-6f) perp = scl3(perp, 1.f/fmaxf(pn, 1e-30f));
  f3 O = (i < L-1) ? add3(C, scl3(perp, 1.24f)) : mk(C.x, C.y + 1.24f, C.z);

  f3 sum = add3(sub3(N,c0), sub3(C,c0));
  f3 cbdir = unit3(mk(-sum.x, -sum.y, -sum.z));
  f3 cb = add3(c0, scl3(cbdir, 1.8f));

  f3 vco = sub3(O, C);
  float nco = fmaxf(nrm3(vco), 1e-8f);

  int sid = seq[i];
  float al = alpha[i];

  float4 pa; pa.x=c0.x; pa.y=c0.y; pa.z=c0.z; pa.w=c_charge[sid];
  float4 pb; pb.x=N.x; pb.y=N.y; pb.z=N.z; pb.w=0.f;
  float4 p1; p1.x=O.x; p1.y=O.y; p1.z=O.z; p1.w=nco;
  float4 p2; p2.x=vco.x; p2.y=vco.y; p2.z=vco.z; p2.w=2.9f*(1.f + 0.1f*(al - 1.f));
  float4 p3; p3.x=cb.x; p3.y=cb.y; p3.z=cb.z; p3.w=0.f;
  WS_PA(ws)[i]=pa; WS_PB(ws)[i]=pb; WS_PI1(ws)[i]=p1; WS_PI2(ws)[i]=p2; WS_PI3(ws)[i]=p3;
  WS_DENS(ws)[i]=0.f;
  WS_DMIN(ws)[i]=0x7F800000u;   // +inf

  // ---- O(L) energy terms ----
  float bond = 0.f, angle = 0.f, rama = 0.f, smooth = 0.f;
  float ent = al * logf(al + 1e-8f);
  if (i < L-1) {
    float alp = alpha[i+1];
    float d = nrm3(sub3(cp, c0));
    float tp = 0.5f*(3.8f*(1.f+0.1f*(al-1.f)) + 3.8f*(1.f+0.1f*(alp-1.f)));
    bond = (d - tp)*(d - tp);
    smooth = (alp - al)*(alp - al);
  }
  if (i >= 1 && i <= L-2) {
    f3 v1 = unit3(sub3(cm, c0));
    f3 v2 = unit3(sub3(cp, c0));
    float cang = dot3(v1, v2);
    float ct = cosf(1.5708f*(1.f + 0.1f*(al - 1.f)));
    angle = (cang - ct)*(cang - ct);

    f3 Cm1 = add3(cm, scl3(vnm, 1.52f));   // Catm[i-1]
    f3 Np1 = sub3(cp, scl3(vni, 1.45f));   // Natm[i+1]
    const float deg = 57.29577951308232f;
    float phi = dihedral(Cm1, N, c0, C) * deg;
    float psi = dihedral(N, c0, C, Np1) * deg;
    float weff = c_wid[sid]*(1.f + 0.1f*(al - 1.f)) + 1e-8f;
    float dphi = (phi - c_phi0[sid]) / weff;
    float dpsi = (psi - c_psi0[sid]) / weff;
    rama = dphi*dphi + dpsi*dpsi;
  }
  bond = wave_reduce(bond); angle = wave_reduce(angle); rama = wave_reduce(rama);
  ent  = wave_reduce(ent);  smooth = wave_reduce(smooth);
  if (threadIdx.x == 0) {
    float* RP = WS_RP(ws);
    int b = blockIdx.x;
    RP[0*64+b]=bond; RP[1*64+b]=angle; RP[2*64+b]=rama; RP[3*64+b]=ent; RP[4*64+b]=smooth;
  }
}

// grid (8,128), 256 threads; each thread handles i0 = bx*512+t and i1 = i0+256
__global__ __launch_bounds__(256) void pair_kernel(float* __restrict__ ws)
{
  const float4* __restrict__ PA  = WS_PA(ws);
  const float4* __restrict__ PB  = WS_PB(ws);
  const float4* __restrict__ PI1 = WS_PI1(ws);
  const float4* __restrict__ PI2 = WS_PI2(ws);
  const float4* __restrict__ PI3 = WS_PI3(ws);

  int t = threadIdx.x;
  int i0 = blockIdx.x*512 + t;
  int i1 = i0 + 256;
  int j0 = blockIdx.y*JC;

  __shared__ float4 sA[JC];   // ca.xyz, q
  __shared__ float4 sB[JC];   // N.xyz, -
  if (t < JC)           sA[t]     = PA[j0 + t];
  else if (t < 2*JC)    sB[t-JC]  = PB[j0 + t - JC];

  float4 a0 = PA[i0],  a1 = PA[i1];
  float4 o0 = PI1[i0], o1 = PI1[i1];
  float4 w0 = PI2[i0], w1 = PI2[i1];
  float4 g0 = PI3[i0], g1 = PI3[i1];
  float rn0 = __builtin_amdgcn_rcpf(o0.w);   // 1/nco
  float rn1 = __builtin_amdgcn_rcpf(o1.w);
  __syncthreads();

  float e_el = 0.f, e_hb = 0.f;
  float dens0 = 0.f, dens1 = 0.f, dm0 = 3.0e38f, dm1 = 3.0e38f;

  #pragma unroll 8
  for (int jj = 0; jj < JC; ++jj) {
    float4 a = sA[jj];
    float4 b = sB[jj];
    int jg = j0 + jj;
    bool self0 = (jg == i0), self1 = (jg == i1);

    // ---- CA distance^2 (density + electro) ----
    float dx0 = a0.x - a.x, dy0 = a0.y - a.y, dz0 = a0.z - a.z;
    float d20 = fmaf(dx0,dx0, fmaf(dy0,dy0, dz0*dz0));
    float dx1 = a1.x - a.x, dy1 = a1.y - a.y, dz1 = a1.z - a.z;
    float d21 = fmaf(dx1,dx1, fmaf(dy1,dy1, dz1*dz1));
    dens0 += (d20 < 100.f) ? 1.f : 0.f;
    dens1 += (d21 < 100.f) ? 1.f : 0.f;

    // ---- CB min-dist^2 ----
    float rx0 = g0.x - a.x, ry0 = g0.y - a.y, rz0 = g0.z - a.z;
    float r20 = fmaf(rx0,rx0, fmaf(ry0,ry0, rz0*rz0));
    dm0 = fminf(dm0, self0 ? 3.0e38f : r20);
    float rx1 = g1.x - a.x, ry1 = g1.y - a.y, rz1 = g1.z - a.z;
    float r21 = fmaf(rx1,rx1, fmaf(ry1,ry1, rz1*rz1));
    dm1 = fminf(dm1, self1 ? 3.0e38f : r21);

    // ---- electrostatics (wave-uniform skip on q_j) ----
    if (a.w != 0.f) {
      float qq0 = self0 ? 0.f : a0.w * a.w;
      float D0  = sqrtf(d20) + 1e-6f;
      e_el += qq0 * __expf(-0.1f*D0) * __builtin_amdgcn_rcpf(80.f*D0);
      float qq1 = self1 ? 0.f : a1.w * a.w;
      float D1  = sqrtf(d21) + 1e-6f;
      e_el += qq1 * __expf(-0.1f*D1) * __builtin_amdgcn_rcpf(80.f*D1);
    }

    // ---- hydrogen bond (rare per-lane; ~15%/wave taken) ----
    float nx0 = b.x - o0.x, ny0 = b.y - o0.y, nz0 = b.z - o0.z;
    float h20 = fmaf(nx0,nx0, fmaf(ny0,ny0, nz0*nz0));
    if (h20 > 6.25f && h20 < 12.25f) {
      float rs  = __builtin_amdgcn_rsqf(h20);
      float Dh  = h20 * rs;
      float num = fmaf(w0.x,nx0, fmaf(w0.y,ny0, w0.z*nz0));
      float tt  = (Dh - w0.w) * 3.33333333333333f;
      e_hb -= num * (rn0 * rs) * __expf(-tt*tt);
    }
    float nx1 = b.x - o1.x, ny1 = b.y - o1.y, nz1 = b.z - o1.z;
    float h21 = fmaf(nx1,nx1, fmaf(ny1,ny1, nz1*nz1));
    if (h21 > 6.25f && h21 < 12.25f) {
      float rs  = __builtin_amdgcn_rsqf(h21);
      float Dh  = h21 * rs;
      float num = fmaf(w1.x,nx1, fmaf(w1.y,ny1, w1.z*nz1));
      float tt  = (Dh - w1.w) * 3.33333333333333f;
      e_hb -= num * (rn1 * rs) * __expf(-tt*tt);
    }
  }

  e_el = wave_reduce(e_el);
  e_hb = wave_reduce(e_hb);
  __shared__ float sp[8];
  if ((t & 63) == 0) { sp[t>>6] = e_el; sp[4+(t>>6)] = e_hb; }
  __syncthreads();
  if (t == 0) {
    int bidx = blockIdx.y*NIB + blockIdx.x;
    WS_BPEL(ws)[bidx] = sp[0]+sp[1]+sp[2]+sp[3];
    WS_BPHB(ws)[bidx] = sp[4]+sp[5]+sp[6]+sp[7];
  }
  atomicAdd(&WS_DENS(ws)[i0], dens0);
  atomicAdd(&WS_DENS(ws)[i1], dens1);
  atomicMin(&WS_DMIN(ws)[i0], __float_as_uint(dm0));
  atomicMin(&WS_DMIN(ws)[i1], __float_as_uint(dm1));
}

// single block, 1024 threads: sum partials + solvent/rotamer + combine
__global__ __launch_bounds__(1024) void final_kernel(const int* __restrict__ seq,
    const float* __restrict__ ws, float* __restrict__ out)
{
  int t = threadIdx.x;
  const float* BPel = WS_BPEL(ws);
  const float* BPhb = WS_BPHB(ws);
  const float* RP = WS_RP(ws);

  float v0=0.f,v1=0.f,v2=0.f,v3=0.f,v4=0.f,v7=0.f,v8=0.f;
  float v5 = BPel[t];   // NBLK == 1024 == blockDim
  float v6 = BPhb[t];
  if (t < 64) { v0=RP[t]; v1=RP[64+t]; v2=RP[128+t]; v3=RP[192+t]; v4=RP[256+t]; }

  #pragma unroll
  for (int k = 0; k < 4; ++k) {
    int i = t + k*1024;
    float density = WS_DENS((float*)ws)[i];
    float burial = 1.f - __expf(-density * 0.05f);
    float hy = c_hydro[seq[i]];
    v7 += (hy > 0.f) ? hy*(1.f - burial) : (-hy*burial);
    float dmin = sqrtf(__uint_as_float(((const unsigned int*)(ws+21*L))[i]));
    if (seq[i] != 5 && i > 0 && i < L-1) v8 += fmaxf(4.f - dmin, 0.f);
  }

  v0=wave_reduce(v0); v1=wave_reduce(v1); v2=wave_reduce(v2);
  v3=wave_reduce(v3); v4=wave_reduce(v4); v5=wave_reduce(v5);
  v6=wave_reduce(v6); v7=wave_reduce(v7); v8=wave_reduce(v8);

  __shared__ float red[16*9];
  int w = t >> 6;
  if ((t & 63) == 0) {
    red[w*9+0]=v0; red[w*9+1]=v1; red[w*9+2]=v2; red[w*9+3]=v3; red[w*9+4]=v4;
    red[w*9+5]=v5; red[w*9+6]=v6; red[w*9+7]=v7; red[w*9+8]=v8;
  }
  __syncthreads();
  if (t == 0) {
    float s[9];
    #pragma unroll
    for (int q = 0; q < 9; ++q) s[q] = 0.f;
    for (int ww = 0; ww < 16; ++ww)
      #pragma unroll
      for (int q = 0; q < 9; ++q) s[q] += red[ww*9+q];
    const float Lf = (float)L;
    out[0] = s[0] / (Lf - 1.f)            // bond
           + s[1] / (Lf - 2.f)            // angle
           + 0.5f * s[2] / (Lf - 2.f)     // rama
           + 0.5f * s[5] / (Lf * Lf)      // electro
           + s[6] / (Lf * Lf)             // hbond
           + 0.5f * s[7] / Lf             // solvent
           + 0.5f * s[8] / (Lf - 2.f)     // rotamer
           + 0.01f * (-s[3] / Lf)         // entropy
           + 0.01f * s[4] / (Lf - 1.f);   // smooth
  }
}

extern "C" void kernel_launch(void* const* d_in, const int* in_sizes, int n_in,
                              void* d_out, int out_size, void* d_ws, size_t ws_size,
                              hipStream_t stream) {
  (void)in_sizes; (void)n_in; (void)out_size; (void)ws_size;
  const float* ca    = (const float*)d_in[0];
  const float* alpha = (const float*)d_in[1];
  const int*   seq   = (const int*)d_in[2];
  float* out = (float*)d_out;
  float* ws  = (float*)d_ws;

  residue_kernel<<<64, 64, 0, stream>>>(ca, alpha, seq, ws);
  pair_kernel<<<dim3(NIB, NJB), 256, 0, stream>>>(ws);
  final_kernel<<<1, 1024, 0, stream>>>(seq, ws, out);
}